// Round 5
// baseline (339.828 us; speedup 1.0000x reference)
//
#include <hip/hip_runtime.h>
#include <hip/hip_bf16.h>

#define BATCH   64
#define LEN     288
#define DIM     256
#define PAST    12
#define NWIN    (LEN - PAST)        // 276
#define M_DIM   (BATCH * NWIN)      // 17664
#define K_DIM   (PAST * DIM)        // 3072
#define N_DIM   3072

#define BM 256
#define BN 256
#define BK 64
#define NTILE   (K_DIM / BK)        // 48
#define NITER   (NTILE / 2)         // 24

#define GRID_N   12
#define BULK_WG  768                 // 64 bm x 12 bn = exactly 3 rounds @256 CU
#define TAIL_M0  16384
#define TAIL_QN  24
#define TAIL_WG  240                 // 10 x 24 quarter tiles (128x128)

typedef __attribute__((ext_vector_type(8)))  short bh8;
typedef __attribute__((ext_vector_type(16))) float f32x16;

__device__ __forceinline__ void llds16(const void* g, void* l) {
    __builtin_amdgcn_global_load_lds(
        (const __attribute__((address_space(1))) unsigned int*)g,
        (__attribute__((address_space(3))) unsigned int*)l,
        16, 0, 0);
}

__global__ void cvt_f32_bf16(const float* __restrict__ in,
                             __hip_bfloat16* __restrict__ out, int n8) {
    int i = blockIdx.x * blockDim.x + threadIdx.x;
    if (i >= n8) return;
    const float4* p = (const float4*)in;
    float4 a = p[2 * i], b = p[2 * i + 1];
    union { __hip_bfloat16 h[8]; int4 v; } u;
    u.h[0] = __float2bfloat16(a.x); u.h[1] = __float2bfloat16(a.y);
    u.h[2] = __float2bfloat16(a.z); u.h[3] = __float2bfloat16(a.w);
    u.h[4] = __float2bfloat16(b.x); u.h[5] = __float2bfloat16(b.y);
    u.h[6] = __float2bfloat16(b.z); u.h[7] = __float2bfloat16(b.w);
    ((int4*)out)[i] = u.v;
}

#define PH_MID  __builtin_amdgcn_sched_barrier(0); __builtin_amdgcn_s_barrier(); \
                __builtin_amdgcn_sched_barrier(0); \
                asm volatile("s_waitcnt lgkmcnt(0)" ::: "memory"); \
                __builtin_amdgcn_sched_barrier(0); __builtin_amdgcn_s_setprio(1);
#define PH_END  __builtin_amdgcn_s_setprio(0); __builtin_amdgcn_sched_barrier(0); \
                __builtin_amdgcn_s_barrier(); __builtin_amdgcn_sched_barrier(0);
#define PH_END_VM(N) __builtin_amdgcn_s_setprio(0); __builtin_amdgcn_sched_barrier(0); \
                asm volatile("s_waitcnt vmcnt(" #N ")" ::: "memory"); \
                __builtin_amdgcn_s_barrier(); __builtin_amdgcn_sched_barrier(0);

// ============================ BULK: 256x256, 32x32x16 MFMA ============================
// LDS unchanged: buf0 A @0 (32KB), buf0 B @32768, buf1 A @65536, buf1 B @98304.
// Per wave: 128x64 out = 4 m-blocks x 2 n-blocks of 32x32. Per K-tile: 4 k-steps (K=16).
// A/B frag: row/col = lane&31, k = (lane>>5)*8 + j. Same XOR swizzle, conflict-free.
#define LDS_A(buf) (smem + (buf) * 65536)
#define LDS_B(buf) (smem + (buf) * 65536 + 32768)

#define RD_A2(buf, MB) { \
    const char* _b = LDS_A(buf) + aRowB + (MB) * 4096; \
    _Pragma("unroll") for (int mb = 0; mb < 2; ++mb) \
    _Pragma("unroll") for (int ks = 0; ks < 4; ++ks) \
        aF[mb][ks] = *(const bh8*)(_b + mb * 4096 + kOf[ks]); }
#define RD_B1(buf, dst, NB) { \
    const char* _b = LDS_B(buf) + bRowB + (NB) * 4096; \
    _Pragma("unroll") for (int ks = 0; ks < 4; ++ks) \
        dst[ks] = *(const bh8*)(_b + kOf[ks]); }
#define MFMA_P(MB, NB, BF) \
    _Pragma("unroll") for (int ks = 0; ks < 4; ++ks) \
    _Pragma("unroll") for (int mb = 0; mb < 2; ++mb) \
        acc[MB + mb][NB] = __builtin_amdgcn_mfma_f32_32x32x16_bf16( \
            aF[mb][ks], BF[ks], acc[MB + mb][NB], 0, 0, 0);
#define STG_A1(buf, kt, q) \
    llds16(Ag + aSrc[q] + (kt) * 64, LDS_A(buf) + (q) * 8192 + wOff);
#define STG_B1(buf, kt, u) \
    llds16(Wg + bSrc[u] + (kt) * 64, LDS_B(buf) + (u) * 8192 + wOff);

__global__ __launch_bounds__(512, 2)
void gemm_bulk(const __hip_bfloat16* __restrict__ Ag,
               const __hip_bfloat16* __restrict__ Wg,
               const float* __restrict__ bias,
               float* __restrict__ C)
{
    extern __shared__ char smem[];

    const int tid = threadIdx.x;
    const int wgid = (blockIdx.x & 7) * (BULK_WG / 8) + (blockIdx.x >> 3);
    const int bm = wgid / GRID_N;
    const int bn = wgid - bm * GRID_N;
    const int tile_m = bm * BM;
    const int tile_n = bn * BN;

    const int rd  = tid >> 3;
    const int chs = (((tid & 7) ^ (rd & 7)) * 8);
    int aSrc[4], bSrc[4];
#pragma unroll
    for (int rb = 0; rb < 4; ++rb) {
        int m  = tile_m + rb * 64 + rd;
        int bq = m / NWIN;
        int wq = m - bq * NWIN;
        aSrc[rb] = (bq * LEN + wq) * DIM + chs;
        bSrc[rb] = (tile_n + rb * 64 + rd) * K_DIM + chs;
    }

    const int wave = tid >> 6, lane = tid & 63;
    const int wm = wave >> 2, wn = wave & 3;
    const int fr31 = lane & 31, kg2 = lane >> 5;
    const int sw = (fr31 & 7) << 4;
    int kOf[4];
#pragma unroll
    for (int ks = 0; ks < 4; ++ks) kOf[ks] = (ks * 32 + kg2 * 16) ^ sw;
    const int aRowB = (wm * 128 + fr31) * 128;
    const int bRowB = (wn * 64 + fr31) * 128;
    const int wOff  = wave * 1024;

    bh8 aF[2][4], bF0[4], bF1[4];
    f32x16 acc[4][2] = {};

    STG_A1(0, 0, 0); STG_A1(0, 0, 1); STG_A1(0, 0, 2); STG_A1(0, 0, 3);
    STG_B1(0, 0, 0); STG_B1(0, 0, 1); STG_B1(0, 0, 2); STG_B1(0, 0, 3);
    STG_A1(1, 1, 0); STG_A1(1, 1, 2);
    STG_B1(1, 1, 0); STG_B1(1, 1, 1);
    STG_A1(1, 1, 1); STG_A1(1, 1, 3);
    asm volatile("s_waitcnt vmcnt(6)" ::: "memory");
    __builtin_amdgcn_s_barrier();
    __builtin_amdgcn_sched_barrier(0);

#pragma unroll 1
    for (int it = 0; it < NITER; ++it) {
        const int b = 2 * it + 1;
        int c = 2 * it + 2; if (c >= NTILE) c = NTILE - 2;
        int d = 2 * it + 3; if (d >= NTILE) d = NTILE - 1;

        // ph0: read A m01 + B n0; stage b.Bu2,Bu3 -> buf1
        RD_A2(0, 0); RD_B1(0, bF0, 0);
        STG_B1(1, b, 2); STG_B1(1, b, 3);
        PH_MID; MFMA_P(0, 0, bF0); PH_END;

        // ph1: read B n1; stage c.Aq0,Aq2 (freed by ph0's A m01 reads)
        RD_B1(0, bF1, 1);
        STG_A1(0, c, 0); STG_A1(0, c, 2);
        PH_MID; MFMA_P(0, 1, bF1); PH_END;

        // ph2: read A m23; stage c.Bu0,Bu1 (B freed after ph1)
        RD_A2(0, 2);
        STG_B1(0, c, 0); STG_B1(0, c, 1);
        PH_MID; MFMA_P(2, 1, bF1); PH_END;

        // ph3: stage c.Aq1,Aq3 (freed by ph2); force tile-b landing
        STG_A1(0, c, 1); STG_A1(0, c, 3);
        PH_MID; MFMA_P(2, 0, bF0); PH_END_VM(6);

        // ph4-7: buf1 (tile b), prefetch d
        RD_A2(1, 0); RD_B1(1, bF0, 0);
        STG_B1(0, c, 2); STG_B1(0, c, 3);
        PH_MID; MFMA_P(0, 0, bF0); PH_END;

        RD_B1(1, bF1, 1);
        STG_A1(1, d, 0); STG_A1(1, d, 2);
        PH_MID; MFMA_P(0, 1, bF1); PH_END;

        RD_A2(1, 2);
        STG_B1(1, d, 0); STG_B1(1, d, 1);
        PH_MID; MFMA_P(2, 1, bF1); PH_END;

        STG_A1(1, d, 1); STG_A1(1, d, 3);
        PH_MID; MFMA_P(2, 0, bF0); PH_END_VM(6);
    }

    // epilogue: 32x32 C/D layout: col=lane&31, row=(reg&3)+8*(reg>>2)+4*(lane>>5)
    float bv[2];
    const float* bp = bias + tile_n + wn * 64 + fr31;
#pragma unroll
    for (int nb = 0; nb < 2; ++nb) bv[nb] = bp[nb * 32];

    const int r0 = kg2 * 4;
#pragma unroll
    for (int mb = 0; mb < 4; ++mb) {
#pragma unroll
        for (int rr = 0; rr < 4; ++rr) {
#pragma unroll
            for (int j = 0; j < 4; ++j) {
                long m = tile_m + wm * 128 + mb * 32 + rr * 8 + r0 + j;
                float* crow = C + m * (long)N_DIM + tile_n + wn * 64 + fr31;
#pragma unroll
                for (int nb = 0; nb < 2; ++nb)
                    __builtin_nontemporal_store(acc[mb][nb][rr * 4 + j] + bv[nb],
                                                &crow[nb * 32]);
            }
        }
    }
}

// ============================ TAIL: 128x128, 32x32x16 ============================
#define TLDS_A(buf) (smem + (buf) * 32768)
#define TLDS_B(buf) (smem + (buf) * 32768 + 16384)

#define T_RD(buf) { \
    const char* _a = TLDS_A(buf) + aRowB; \
    _Pragma("unroll") for (int mb = 0; mb < 2; ++mb) \
    _Pragma("unroll") for (int ks = 0; ks < 4; ++ks) \
        aF[mb][ks] = *(const bh8*)(_a + mb * 4096 + kOf[ks]); \
    const char* _bb = TLDS_B(buf) + bRowB; \
    _Pragma("unroll") for (int ks = 0; ks < 4; ++ks) \
        bF[ks] = *(const bh8*)(_bb + kOf[ks]); }
#define T_MFMA(MB) \
    _Pragma("unroll") for (int ks = 0; ks < 4; ++ks) \
        acc[MB] = __builtin_amdgcn_mfma_f32_32x32x16_bf16( \
            aF[MB][ks], bF[ks], acc[MB], 0, 0, 0);
#define T_STG_A(buf, kt, u) \
    llds16(Ag + aSrc[u] + (kt) * 64, TLDS_A(buf) + (u) * 8192 + wOff);
#define T_STG_B(buf, kt, u) \
    llds16(Wg + bSrc[u] + (kt) * 64, TLDS_B(buf) + (u) * 8192 + wOff);

__global__ __launch_bounds__(512, 2)
void gemm_tail(const __hip_bfloat16* __restrict__ Ag,
               const __hip_bfloat16* __restrict__ Wg,
               const float* __restrict__ bias,
               float* __restrict__ C)
{
    extern __shared__ char smem[];

    const int tid = threadIdx.x;
    const int wgid = (blockIdx.x & 7) * (TAIL_WG / 8) + (blockIdx.x >> 3);
    const int qm = wgid / TAIL_QN;
    const int qn = wgid - qm * TAIL_QN;
    const int tile_m = TAIL_M0 + qm * 128;
    const int tile_n = qn * 128;

    const int rd  = tid >> 3;
    const int chs = (((tid & 7) ^ (rd & 7)) * 8);
    int aSrc[2], bSrc[2];
#pragma unroll
    for (int rb = 0; rb < 2; ++rb) {
        int m  = tile_m + rb * 64 + rd;
        int bq = m / NWIN;
        int wq = m - bq * NWIN;
        aSrc[rb] = (bq * LEN + wq) * DIM + chs;
        bSrc[rb] = (tile_n + rb * 64 + rd) * K_DIM + chs;
    }

    const int wave = tid >> 6, lane = tid & 63;
    const int wm = wave >> 2, wn = wave & 3;             // per-wave 64x32
    const int fr31 = lane & 31, kg2 = lane >> 5;
    const int sw = (fr31 & 7) << 4;
    int kOf[4];
#pragma unroll
    for (int ks = 0; ks < 4; ++ks) kOf[ks] = (ks * 32 + kg2 * 16) ^ sw;
    const int aRowB = (wm * 64 + fr31) * 128;
    const int bRowB = (wn * 32 + fr31) * 128;
    const int wOff  = wave * 1024;

    bh8 aF[2][4], bF[4];
    f32x16 acc[2] = {};

    T_STG_A(0, 0, 0); T_STG_A(0, 0, 1); T_STG_B(0, 0, 0); T_STG_B(0, 0, 1);
    T_STG_A(1, 1, 0); T_STG_A(1, 1, 1);
    asm volatile("s_waitcnt vmcnt(2)" ::: "memory");
    __builtin_amdgcn_s_barrier();
    __builtin_amdgcn_sched_barrier(0);

#pragma unroll 1
    for (int it = 0; it < NITER; ++it) {
        const int b = 2 * it + 1;
        int c = 2 * it + 2; if (c >= NTILE) c = NTILE - 2;
        int d = 2 * it + 3; if (d >= NTILE) d = NTILE - 1;

        T_RD(0);
        T_STG_B(1, b, 0); T_STG_B(1, b, 1);
        PH_MID; T_MFMA(0); PH_END;

        T_STG_A(0, c, 0); T_STG_A(0, c, 1);
        PH_MID; T_MFMA(1); PH_END_VM(2);

        T_RD(1);
        T_STG_B(0, c, 0); T_STG_B(0, c, 1);
        PH_MID; T_MFMA(0); PH_END;

        T_STG_A(1, d, 0); T_STG_A(1, d, 1);
        PH_MID; T_MFMA(1); PH_END_VM(2);
    }

    float bv = bias[tile_n + wn * 32 + fr31];
    const int r0 = kg2 * 4;
#pragma unroll
    for (int mb = 0; mb < 2; ++mb) {
#pragma unroll
        for (int rr = 0; rr < 4; ++rr) {
#pragma unroll
            for (int j = 0; j < 4; ++j) {
                long m = tile_m + wm * 64 + mb * 32 + rr * 8 + r0 + j;
                float* crow = C + m * (long)N_DIM + tile_n + wn * 32 + fr31;
                __builtin_nontemporal_store(acc[mb][rr * 4 + j] + bv, crow);
            }
        }
    }
}

extern "C" void kernel_launch(void* const* d_in, const int* in_sizes, int n_in,
                              void* d_out, int out_size, void* d_ws, size_t ws_size,
                              hipStream_t stream) {
    const float* inp  = (const float*)d_in[0];
    const float* Wf   = (const float*)d_in[1];
    const float* bias = (const float*)d_in[2];
    float* out = (float*)d_out;

    __hip_bfloat16* Abf = (__hip_bfloat16*)d_ws;
    __hip_bfloat16* Wbf = (__hip_bfloat16*)((char*)d_ws + (size_t)BATCH * LEN * DIM * 2);

    const int nA8 = BATCH * LEN * DIM / 8;
    const int nW8 = N_DIM * K_DIM / 8;
    cvt_f32_bf16<<<(nA8 + 255) / 256, 256, 0, stream>>>(inp, Abf, nA8);
    cvt_f32_bf16<<<(nW8 + 255) / 256, 256, 0, stream>>>(Wf, Wbf, nW8);

    hipFuncSetAttribute((const void*)gemm_bulk,
                        hipFuncAttributeMaxDynamicSharedMemorySize, 131072);
    hipFuncSetAttribute((const void*)gemm_tail,
                        hipFuncAttributeMaxDynamicSharedMemorySize, 65536);
    gemm_bulk<<<dim3(BULK_WG), 512, 131072, stream>>>(Abf, Wbf, bias, out);
    gemm_tail<<<dim3(TAIL_WG), 512, 65536, stream>>>(Abf, Wbf, bias, out);
}

// Round 6
// 308.364 us; speedup vs baseline: 1.1020x; 1.1020x over previous
//
#include <hip/hip_runtime.h>
#include <hip/hip_bf16.h>

#define BATCH   64
#define LEN     288
#define DIM     256
#define PAST    12
#define NWIN    (LEN - PAST)        // 276
#define M_DIM   (BATCH * NWIN)      // 17664
#define K_DIM   (PAST * DIM)        // 3072
#define N_DIM   3072

#define BM 256
#define BN 256
#define BK 64
#define NTILE   (K_DIM / BK)        // 48
#define NITER   (NTILE / 2)         // 24

#define GRID_N   12
#define BULK_WG  768                 // 64 bm x 12 bn = exactly 3 rounds @256 CU
#define TAIL_M0  16384
#define TAIL_QN  24
#define TAIL_WG  240                 // 10 x 24 quarter tiles (128x128)

typedef __attribute__((ext_vector_type(8))) short bh8;
typedef __attribute__((ext_vector_type(4))) float f32x4;

__device__ __forceinline__ void llds16(const void* g, void* l) {
    __builtin_amdgcn_global_load_lds(
        (const __attribute__((address_space(1))) unsigned int*)g,
        (__attribute__((address_space(3))) unsigned int*)l,
        16, 0, 0);
}

__global__ void cvt_f32_bf16(const float* __restrict__ in,
                             __hip_bfloat16* __restrict__ out, int n8) {
    int i = blockIdx.x * blockDim.x + threadIdx.x;
    if (i >= n8) return;
    const float4* p = (const float4*)in;
    float4 a = p[2 * i], b = p[2 * i + 1];
    union { __hip_bfloat16 h[8]; int4 v; } u;
    u.h[0] = __float2bfloat16(a.x); u.h[1] = __float2bfloat16(a.y);
    u.h[2] = __float2bfloat16(a.z); u.h[3] = __float2bfloat16(a.w);
    u.h[4] = __float2bfloat16(b.x); u.h[5] = __float2bfloat16(b.y);
    u.h[6] = __float2bfloat16(b.z); u.h[7] = __float2bfloat16(b.w);
    ((int4*)out)[i] = u.v;
}

// PH_MID: NO forced lgkmcnt(0) — ds_reads are compiler-visible loads; hipcc
// emits counted lgkmcnt before each first use, overlapping drain with MFMA.
#define PH_MID  __builtin_amdgcn_sched_barrier(0); __builtin_amdgcn_s_barrier(); \
                __builtin_amdgcn_sched_barrier(0); __builtin_amdgcn_s_setprio(1);
#define PH_END  __builtin_amdgcn_s_setprio(0); __builtin_amdgcn_sched_barrier(0); \
                __builtin_amdgcn_s_barrier(); __builtin_amdgcn_sched_barrier(0);
#define PH_END_VM(N) __builtin_amdgcn_s_setprio(0); __builtin_amdgcn_sched_barrier(0); \
                asm volatile("s_waitcnt vmcnt(" #N ")" ::: "memory"); \
                __builtin_amdgcn_s_barrier(); __builtin_amdgcn_sched_barrier(0);

// ============================ BULK: 256x256, 16x16x32 ============================
#define LDS_A(buf) (smem + (buf) * 65536)
#define LDS_B(buf) (smem + (buf) * 65536 + 32768)

#define RD_A4(buf, MB) { \
    const char* _b = LDS_A(buf) + aRowB; \
    _Pragma("unroll") for (int mi = 0; mi < 4; ++mi) { \
        a0[mi][0] = *(const bh8*)(_b + (MB + mi) * 2048 + kOff0); \
        a0[mi][1] = *(const bh8*)(_b + (MB + mi) * 2048 + kOff1); \
    } }
#define RD_B2(buf, dst, NB) { \
    const char* _b = LDS_B(buf) + bRowB; \
    _Pragma("unroll") for (int ni = 0; ni < 2; ++ni) { \
        dst[ni][0] = *(const bh8*)(_b + (NB + ni) * 2048 + kOff0); \
        dst[ni][1] = *(const bh8*)(_b + (NB + ni) * 2048 + kOff1); \
    } }
#define MFMA_Q(MB, NB, BB) \
    _Pragma("unroll") for (int mi = 0; mi < 4; ++mi) \
    _Pragma("unroll") for (int ni = 0; ni < 2; ++ni) { \
        acc[MB + mi][NB + ni] = __builtin_amdgcn_mfma_f32_16x16x32_bf16( \
            a0[mi][0], BB[ni][0], acc[MB + mi][NB + ni], 0, 0, 0); \
        acc[MB + mi][NB + ni] = __builtin_amdgcn_mfma_f32_16x16x32_bf16( \
            a0[mi][1], BB[ni][1], acc[MB + mi][NB + ni], 0, 0, 0); \
    }
#define STG_A1(buf, kt, q) \
    llds16(Ag + aSrc[q] + (kt) * 64, LDS_A(buf) + (q) * 8192 + wOff);
#define STG_B1(buf, kt, u) \
    llds16(Wg + bSrc[u] + (kt) * 64, LDS_B(buf) + (u) * 8192 + wOff);

__global__ __launch_bounds__(512, 2)
void gemm_bulk(const __hip_bfloat16* __restrict__ Ag,
               const __hip_bfloat16* __restrict__ Wg,
               const float* __restrict__ bias,
               float* __restrict__ C)
{
    extern __shared__ char smem[];

    const int tid = threadIdx.x;
    const int wgid = (blockIdx.x & 7) * (BULK_WG / 8) + (blockIdx.x >> 3);
    const int bm = wgid / GRID_N;
    const int bn = wgid - bm * GRID_N;
    const int tile_m = bm * BM;
    const int tile_n = bn * BN;

    const int rd  = tid >> 3;
    const int chs = (((tid & 7) ^ (rd & 7)) * 8);
    int aSrc[4], bSrc[4];
#pragma unroll
    for (int rb = 0; rb < 4; ++rb) {
        int m  = tile_m + rb * 64 + rd;
        int bq = m / NWIN;
        int wq = m - bq * NWIN;
        aSrc[rb] = (bq * LEN + wq) * DIM + chs;
        bSrc[rb] = (tile_n + rb * 64 + rd) * K_DIM + chs;
    }

    const int wave = tid >> 6, lane = tid & 63;
    const int wm = wave >> 2, wn = wave & 3;
    const int fr = lane & 15, kg = lane >> 4;
    const int sw    = (fr & 7) << 4;
    const int kOff0 = (kg * 16) ^ sw;
    const int kOff1 = kOff0 ^ 64;
    const int aRowB = (wm * 128 + fr) * 128;
    const int bRowB = (wn * 64 + fr) * 128;
    const int wOff  = wave * 1024;

    bh8 a0[4][2], fb0[2][2], fb1[2][2];
    f32x4 acc[8][4] = {};

    STG_A1(0, 0, 0); STG_A1(0, 0, 1); STG_A1(0, 0, 2); STG_A1(0, 0, 3);
    STG_B1(0, 0, 0); STG_B1(0, 0, 1); STG_B1(0, 0, 2); STG_B1(0, 0, 3);
    STG_A1(1, 1, 0); STG_A1(1, 1, 2);
    STG_B1(1, 1, 0); STG_B1(1, 1, 1);
    STG_A1(1, 1, 1); STG_A1(1, 1, 3);
    asm volatile("s_waitcnt vmcnt(6)" ::: "memory");
    __builtin_amdgcn_s_barrier();
    __builtin_amdgcn_sched_barrier(0);

#pragma unroll 1
    for (int it = 0; it < NITER; ++it) {
        const int b = 2 * it + 1;
        int c = 2 * it + 2; if (c >= NTILE) c = NTILE - 2;
        int d = 2 * it + 3; if (d >= NTILE) d = NTILE - 1;

        // ph0: B-frags first (consumed first), then A; stage b.Bu2,Bu3 -> buf1
        RD_B2(0, fb0, 0); RD_A4(0, 0);
        STG_B1(1, b, 2); STG_B1(1, b, 3);
        PH_MID; MFMA_Q(0, 0, fb0); PH_END;

        RD_B2(0, fb1, 2);
        STG_A1(0, c, 0); STG_A1(0, c, 2);
        PH_MID; MFMA_Q(0, 2, fb1); PH_END;

        RD_A4(0, 4);
        STG_B1(0, c, 0); STG_B1(0, c, 1);
        PH_MID; MFMA_Q(4, 2, fb1); PH_END;

        STG_A1(0, c, 1); STG_A1(0, c, 3);
        PH_MID; MFMA_Q(4, 0, fb0); PH_END_VM(6);

        // ph4-7: buf1 (tile b), prefetch d
        RD_B2(1, fb0, 0); RD_A4(1, 0);
        STG_B1(0, c, 2); STG_B1(0, c, 3);
        PH_MID; MFMA_Q(0, 0, fb0); PH_END;

        RD_B2(1, fb1, 2);
        STG_A1(1, d, 0); STG_A1(1, d, 2);
        PH_MID; MFMA_Q(0, 2, fb1); PH_END;

        RD_A4(1, 4);
        STG_B1(1, d, 0); STG_B1(1, d, 1);
        PH_MID; MFMA_Q(4, 2, fb1); PH_END;

        STG_A1(1, d, 1); STG_A1(1, d, 3);
        PH_MID; MFMA_Q(4, 0, fb0); PH_END_VM(6);
    }

    float bv[4];
    const float* bp = bias + tile_n + wn * 64 + fr;
#pragma unroll
    for (int ni = 0; ni < 4; ++ni) bv[ni] = bp[ni * 16];

    const int r0 = (lane >> 4) * 4;
#pragma unroll
    for (int mi = 0; mi < 8; ++mi) {
#pragma unroll
        for (int j = 0; j < 4; ++j) {
            long m = tile_m + wm * 128 + mi * 16 + r0 + j;
            float* crow = C + m * (long)N_DIM + tile_n + wn * 64 + fr;
#pragma unroll
            for (int ni = 0; ni < 4; ++ni)
                __builtin_nontemporal_store(acc[mi][ni][j] + bv[ni], &crow[ni * 16]);
        }
    }
}

// ============================ TAIL: 128x128, 16x16x32 ============================
#define TLDS_A(buf) (smem + (buf) * 32768)
#define TLDS_B(buf) (smem + (buf) * 32768 + 16384)

#define T_RD(buf) { \
    const char* _bb = TLDS_B(buf) + bRowB; \
    _Pragma("unroll") for (int ni = 0; ni < 2; ++ni) { \
        fb0[ni][0] = *(const bh8*)(_bb + ni * 2048 + kOff0); \
        fb0[ni][1] = *(const bh8*)(_bb + ni * 2048 + kOff1); \
    } \
    const char* _a = TLDS_A(buf) + aRowB; \
    _Pragma("unroll") for (int mi = 0; mi < 4; ++mi) { \
        a0[mi][0] = *(const bh8*)(_a + mi * 2048 + kOff0); \
        a0[mi][1] = *(const bh8*)(_a + mi * 2048 + kOff1); \
    } }
#define T_MFMA(MB) \
    _Pragma("unroll") for (int mi = 0; mi < 2; ++mi) \
    _Pragma("unroll") for (int ni = 0; ni < 2; ++ni) { \
        acc[MB + mi][ni] = __builtin_amdgcn_mfma_f32_16x16x32_bf16( \
            a0[MB + mi][0], fb0[ni][0], acc[MB + mi][ni], 0, 0, 0); \
        acc[MB + mi][ni] = __builtin_amdgcn_mfma_f32_16x16x32_bf16( \
            a0[MB + mi][1], fb0[ni][1], acc[MB + mi][ni], 0, 0, 0); \
    }
#define T_STG_A(buf, kt, u) \
    llds16(Ag + aSrc[u] + (kt) * 64, TLDS_A(buf) + (u) * 8192 + wOff);
#define T_STG_B(buf, kt, u) \
    llds16(Wg + bSrc[u] + (kt) * 64, TLDS_B(buf) + (u) * 8192 + wOff);

__global__ __launch_bounds__(512, 2)
void gemm_tail(const __hip_bfloat16* __restrict__ Ag,
               const __hip_bfloat16* __restrict__ Wg,
               const float* __restrict__ bias,
               float* __restrict__ C)
{
    extern __shared__ char smem[];

    const int tid = threadIdx.x;
    const int wgid = (blockIdx.x & 7) * (TAIL_WG / 8) + (blockIdx.x >> 3);
    const int qm = wgid / TAIL_QN;
    const int qn = wgid - qm * TAIL_QN;
    const int tile_m = TAIL_M0 + qm * 128;
    const int tile_n = qn * 128;

    const int rd  = tid >> 3;
    const int chs = (((tid & 7) ^ (rd & 7)) * 8);
    int aSrc[2], bSrc[2];
#pragma unroll
    for (int rb = 0; rb < 2; ++rb) {
        int m  = tile_m + rb * 64 + rd;
        int bq = m / NWIN;
        int wq = m - bq * NWIN;
        aSrc[rb] = (bq * LEN + wq) * DIM + chs;
        bSrc[rb] = (tile_n + rb * 64 + rd) * K_DIM + chs;
    }

    const int wave = tid >> 6, lane = tid & 63;
    const int wm = wave >> 2, wn = wave & 3;             // per-wave 64x32
    const int fr = lane & 15, kg = lane >> 4;
    const int sw    = (fr & 7) << 4;
    const int kOff0 = (kg * 16) ^ sw;
    const int kOff1 = kOff0 ^ 64;
    const int aRowB = (wm * 64 + fr) * 128;
    const int bRowB = (wn * 32 + fr) * 128;
    const int wOff  = wave * 1024;

    bh8 a0[4][2], fb0[2][2];
    f32x4 acc[4][2] = {};

    T_STG_A(0, 0, 0); T_STG_A(0, 0, 1); T_STG_B(0, 0, 0); T_STG_B(0, 0, 1);
    T_STG_A(1, 1, 0); T_STG_A(1, 1, 1);
    asm volatile("s_waitcnt vmcnt(2)" ::: "memory");
    __builtin_amdgcn_s_barrier();
    __builtin_amdgcn_sched_barrier(0);

#pragma unroll 1
    for (int it = 0; it < NITER; ++it) {
        const int b = 2 * it + 1;
        int c = 2 * it + 2; if (c >= NTILE) c = NTILE - 2;
        int d = 2 * it + 3; if (d >= NTILE) d = NTILE - 1;

        T_RD(0);
        T_STG_B(1, b, 0); T_STG_B(1, b, 1);
        PH_MID; T_MFMA(0); PH_END;

        T_STG_A(0, c, 0); T_STG_A(0, c, 1);
        PH_MID; T_MFMA(2); PH_END_VM(2);

        T_RD(1);
        T_STG_B(0, c, 0); T_STG_B(0, c, 1);
        PH_MID; T_MFMA(0); PH_END;

        T_STG_A(1, d, 0); T_STG_A(1, d, 1);
        PH_MID; T_MFMA(2); PH_END_VM(2);
    }

    float bv[2];
    const float* bp = bias + tile_n + wn * 32 + fr;
#pragma unroll
    for (int ni = 0; ni < 2; ++ni) bv[ni] = bp[ni * 16];

    const int r0 = (lane >> 4) * 4;
#pragma unroll
    for (int mi = 0; mi < 4; ++mi) {
#pragma unroll
        for (int j = 0; j < 4; ++j) {
            long m = tile_m + wm * 64 + mi * 16 + r0 + j;
            float* crow = C + m * (long)N_DIM + tile_n + wn * 32 + fr;
#pragma unroll
            for (int ni = 0; ni < 2; ++ni)
                __builtin_nontemporal_store(acc[mi][ni][j] + bv[ni], &crow[ni * 16]);
        }
    }
}

extern "C" void kernel_launch(void* const* d_in, const int* in_sizes, int n_in,
                              void* d_out, int out_size, void* d_ws, size_t ws_size,
                              hipStream_t stream) {
    const float* inp  = (const float*)d_in[0];
    const float* Wf   = (const float*)d_in[1];
    const float* bias = (const float*)d_in[2];
    float* out = (float*)d_out;

    __hip_bfloat16* Abf = (__hip_bfloat16*)d_ws;
    __hip_bfloat16* Wbf = (__hip_bfloat16*)((char*)d_ws + (size_t)BATCH * LEN * DIM * 2);

    const int nA8 = BATCH * LEN * DIM / 8;
    const int nW8 = N_DIM * K_DIM / 8;
    cvt_f32_bf16<<<(nA8 + 255) / 256, 256, 0, stream>>>(inp, Abf, nA8);
    cvt_f32_bf16<<<(nW8 + 255) / 256, 256, 0, stream>>>(Wf, Wbf, nW8);

    hipFuncSetAttribute((const void*)gemm_bulk,
                        hipFuncAttributeMaxDynamicSharedMemorySize, 131072);
    hipFuncSetAttribute((const void*)gemm_tail,
                        hipFuncAttributeMaxDynamicSharedMemorySize, 65536);
    gemm_bulk<<<dim3(BULK_WG), 512, 131072, stream>>>(Abf, Wbf, bias, out);
    gemm_tail<<<dim3(TAIL_WG), 512, 65536, stream>>>(Abf, Wbf, bias, out);
}

// Round 7
// 308.056 us; speedup vs baseline: 1.1031x; 1.0010x over previous
//
#include <hip/hip_runtime.h>
#include <hip/hip_bf16.h>

#define BATCH   64
#define LEN     288
#define DIM     256
#define PAST    12
#define NWIN    (LEN - PAST)        // 276
#define M_DIM   (BATCH * NWIN)      // 17664
#define K_DIM   (PAST * DIM)        // 3072
#define N_DIM   3072

#define BM 256
#define BN 256
#define BK 64
#define NTILE   (K_DIM / BK)        // 48
#define NITER   (NTILE / 2)         // 24

#define GRID_N   12
#define BULK_WG  768                 // 64 bm x 12 bn = exactly 3 rounds @256 CU
#define TAIL_M0  16384
#define TAIL_QN  24
#define TAIL_WG  240                 // 10 x 24 quarter tiles (128x128)

typedef __attribute__((ext_vector_type(8))) short bh8;
typedef __attribute__((ext_vector_type(4))) float f32x4;

__device__ __forceinline__ void llds16(const void* g, void* l) {
    __builtin_amdgcn_global_load_lds(
        (const __attribute__((address_space(1))) unsigned int*)g,
        (__attribute__((address_space(3))) unsigned int*)l,
        16, 0, 0);
}

__global__ void cvt_f32_bf16(const float* __restrict__ in,
                             __hip_bfloat16* __restrict__ out, int n8) {
    int i = blockIdx.x * blockDim.x + threadIdx.x;
    if (i >= n8) return;
    const float4* p = (const float4*)in;
    float4 a = p[2 * i], b = p[2 * i + 1];
    union { __hip_bfloat16 h[8]; int4 v; } u;
    u.h[0] = __float2bfloat16(a.x); u.h[1] = __float2bfloat16(a.y);
    u.h[2] = __float2bfloat16(a.z); u.h[3] = __float2bfloat16(a.w);
    u.h[4] = __float2bfloat16(b.x); u.h[5] = __float2bfloat16(b.y);
    u.h[6] = __float2bfloat16(b.z); u.h[7] = __float2bfloat16(b.w);
    ((int4*)out)[i] = u.v;
}

#define PH_MID  __builtin_amdgcn_sched_barrier(0); __builtin_amdgcn_s_barrier(); \
                __builtin_amdgcn_sched_barrier(0); __builtin_amdgcn_s_setprio(1);
#define PH_END  __builtin_amdgcn_s_setprio(0); __builtin_amdgcn_sched_barrier(0); \
                __builtin_amdgcn_s_barrier(); __builtin_amdgcn_sched_barrier(0);
#define PH_END_VM(N) __builtin_amdgcn_s_setprio(0); __builtin_amdgcn_sched_barrier(0); \
                asm volatile("s_waitcnt vmcnt(" #N ")" ::: "memory"); \
                __builtin_amdgcn_s_barrier(); __builtin_amdgcn_sched_barrier(0);

// ============================ BULK: 256x256, 16x16x32 ============================
// READ-AHEAD schedule: phase p's pre-region issues the fragment reads consumed
// by phase p+1's MFMA (k-split quadrants: 4m x 4n x 1k = 16 MFMA/phase).
// Ping-pong sets aP/aQ, bP/bQ -> no extra VGPRs vs in-phase reads.
// Staging identical to R4-proven region-freed discipline; vmcnt(4) fences at
// ph2/ph6 ends force the next-read tile's landing BEFORE its read-ahead phase.
#define LDS_A(buf) (smem + (buf) * 65536)
#define LDS_B(buf) (smem + (buf) * 65536 + 32768)

#define RD_AK(buf, MB, KO, dst) { \
    const char* _b = LDS_A(buf) + aRowB; \
    _Pragma("unroll") for (int mi = 0; mi < 4; ++mi) \
        dst[mi] = *(const bh8*)(_b + ((MB) + mi) * 2048 + (KO)); }
#define RD_BK(buf, KO, dst) { \
    const char* _b = LDS_B(buf) + bRowB; \
    _Pragma("unroll") for (int ni = 0; ni < 4; ++ni) \
        dst[ni] = *(const bh8*)(_b + ni * 2048 + (KO)); }
#define MFMA_K(MB, AS, BS) \
    _Pragma("unroll") for (int mi = 0; mi < 4; ++mi) \
    _Pragma("unroll") for (int ni = 0; ni < 4; ++ni) \
        acc[(MB) + mi][ni] = __builtin_amdgcn_mfma_f32_16x16x32_bf16( \
            AS[mi], BS[ni], acc[(MB) + mi][ni], 0, 0, 0);
#define STG_A1(buf, kt, q) \
    llds16(Ag + aSrc[q] + (kt) * 64, LDS_A(buf) + (q) * 8192 + wOff);
#define STG_B1(buf, kt, u) \
    llds16(Wg + bSrc[u] + (kt) * 64, LDS_B(buf) + (u) * 8192 + wOff);

__global__ __launch_bounds__(512, 2)
void gemm_bulk(const __hip_bfloat16* __restrict__ Ag,
               const __hip_bfloat16* __restrict__ Wg,
               const float* __restrict__ bias,
               float* __restrict__ C)
{
    extern __shared__ char smem[];

    const int tid = threadIdx.x;
    const int wgid = (blockIdx.x & 7) * (BULK_WG / 8) + (blockIdx.x >> 3);
    const int bm = wgid / GRID_N;
    const int bn = wgid - bm * GRID_N;
    const int tile_m = bm * BM;
    const int tile_n = bn * BN;

    const int rd  = tid >> 3;
    const int chs = (((tid & 7) ^ (rd & 7)) * 8);
    int aSrc[4], bSrc[4];
#pragma unroll
    for (int rb = 0; rb < 4; ++rb) {
        int m  = tile_m + rb * 64 + rd;
        int bq = m / NWIN;
        int wq = m - bq * NWIN;
        aSrc[rb] = (bq * LEN + wq) * DIM + chs;
        bSrc[rb] = (tile_n + rb * 64 + rd) * K_DIM + chs;
    }

    const int wave = tid >> 6, lane = tid & 63;
    const int wm = wave >> 2, wn = wave & 3;
    const int fr = lane & 15, kg = lane >> 4;
    const int sw    = (fr & 7) << 4;
    const int kOff0 = (kg * 16) ^ sw;
    const int kOff1 = kOff0 ^ 64;
    const int aRowB = (wm * 128 + fr) * 128;
    const int bRowB = (wn * 64 + fr) * 128;
    const int wOff  = wave * 1024;

    bh8 aP[4], aQ[4], bP[4], bQ[4];
    f32x4 acc[8][4] = {};

    // prologue: tile0 (8 units) -> buf0; tile1 first 6 units -> buf1
    STG_A1(0, 0, 0); STG_A1(0, 0, 1); STG_A1(0, 0, 2); STG_A1(0, 0, 3);
    STG_B1(0, 0, 0); STG_B1(0, 0, 1); STG_B1(0, 0, 2); STG_B1(0, 0, 3);
    STG_A1(1, 1, 0); STG_A1(1, 1, 2);
    STG_B1(1, 1, 0); STG_B1(1, 1, 1);
    STG_A1(1, 1, 1); STG_A1(1, 1, 3);
    asm volatile("s_waitcnt vmcnt(6)" ::: "memory");     // tile0 landed
    __builtin_amdgcn_s_barrier();
    __builtin_amdgcn_sched_barrier(0);

    // pre-loop read-ahead for ph0: A mLo k0, B k0 (tile0)
    RD_AK(0, 0, kOff0, aP); RD_BK(0, kOff0, bP);

#pragma unroll 1
    for (int it = 0; it < NITER; ++it) {
        const int b = 2 * it + 1;
        int c = 2 * it + 2; if (c >= NTILE) c = NTILE - 2;   // same-bytes rewrite
        int d = 2 * it + 3; if (d >= NTILE) d = NTILE - 1;

        // ph0: rd {A mLo k1, B k1}; stage b.Bu2,Bu3 | MFMA mLo k0 (aP,bP)
        RD_AK(0, 0, kOff1, aQ); RD_BK(0, kOff1, bQ);
        STG_B1(1, b, 2); STG_B1(1, b, 3);
        PH_MID; MFMA_K(0, aP, bP); PH_END;

        // ph1: rd {A mHi k0}; stage c.Aq0,Aq2 | MFMA mLo k1 (aQ,bQ)
        RD_AK(0, 4, kOff0, aP);
        STG_A1(0, c, 0); STG_A1(0, c, 2);
        PH_MID; MFMA_K(0, aQ, bQ); PH_END;

        // ph2: rd {A mHi k1}; stage c.Bu0,Bu1 | MFMA mHi k0 (aP,bP)
        RD_AK(0, 4, kOff1, aQ);
        STG_B1(0, c, 0); STG_B1(0, c, 1);
        PH_MID; MFMA_K(4, aP, bP); PH_END_VM(4);   // force tile-b fully landed

        // ph3: rd {b: A mLo k0, B k0}; stage c.Aq1,Aq3 | MFMA mHi k1 (aQ,bQ)
        RD_AK(1, 0, kOff0, aP); RD_BK(1, kOff0, bP);
        STG_A1(0, c, 1); STG_A1(0, c, 3);
        PH_MID; MFMA_K(4, aQ, bQ); PH_END;

        // ph4: rd {b: A mLo k1, B k1}; stage c.Bu2,Bu3 | MFMA mLo k0
        RD_AK(1, 0, kOff1, aQ); RD_BK(1, kOff1, bQ);
        STG_B1(0, c, 2); STG_B1(0, c, 3);
        PH_MID; MFMA_K(0, aP, bP); PH_END;

        // ph5: rd {b: A mHi k0}; stage d.Aq0,Aq2 | MFMA mLo k1
        RD_AK(1, 4, kOff0, aP);
        STG_A1(1, d, 0); STG_A1(1, d, 2);
        PH_MID; MFMA_K(0, aQ, bQ); PH_END;

        // ph6: rd {b: A mHi k1}; stage d.Bu0,Bu1 | MFMA mHi k0
        RD_AK(1, 4, kOff1, aQ);
        STG_B1(1, d, 0); STG_B1(1, d, 1);
        PH_MID; MFMA_K(4, aP, bP); PH_END_VM(4);   // force tile-c fully landed

        // ph7: rd {c: A mLo k0, B k0} (next iter ph0); stage d.Aq1,Aq3 | MFMA mHi k1
        RD_AK(0, 0, kOff0, aP); RD_BK(0, kOff0, bP);
        STG_A1(1, d, 1); STG_A1(1, d, 3);
        PH_MID; MFMA_K(4, aQ, bQ); PH_END;
    }

    float bv[4];
    const float* bp = bias + tile_n + wn * 64 + fr;
#pragma unroll
    for (int ni = 0; ni < 4; ++ni) bv[ni] = bp[ni * 16];

    const int r0 = (lane >> 4) * 4;
#pragma unroll
    for (int mi = 0; mi < 8; ++mi) {
#pragma unroll
        for (int j = 0; j < 4; ++j) {
            long m = tile_m + wm * 128 + mi * 16 + r0 + j;
            float* crow = C + m * (long)N_DIM + tile_n + wn * 64 + fr;
#pragma unroll
            for (int ni = 0; ni < 4; ++ni)
                __builtin_nontemporal_store(acc[mi][ni][j] + bv[ni], &crow[ni * 16]);
        }
    }
}

// ============================ TAIL: 128x128, 16x16x32 ============================
#define TLDS_A(buf) (smem + (buf) * 32768)
#define TLDS_B(buf) (smem + (buf) * 32768 + 16384)

#define T_RD(buf) { \
    const char* _bb = TLDS_B(buf) + bRowB; \
    _Pragma("unroll") for (int ni = 0; ni < 2; ++ni) { \
        fb0[ni][0] = *(const bh8*)(_bb + ni * 2048 + kOff0); \
        fb0[ni][1] = *(const bh8*)(_bb + ni * 2048 + kOff1); \
    } \
    const char* _a = TLDS_A(buf) + aRowB; \
    _Pragma("unroll") for (int mi = 0; mi < 4; ++mi) { \
        a0[mi][0] = *(const bh8*)(_a + mi * 2048 + kOff0); \
        a0[mi][1] = *(const bh8*)(_a + mi * 2048 + kOff1); \
    } }
#define T_MFMA(MB) \
    _Pragma("unroll") for (int mi = 0; mi < 2; ++mi) \
    _Pragma("unroll") for (int ni = 0; ni < 2; ++ni) { \
        acc[MB + mi][ni] = __builtin_amdgcn_mfma_f32_16x16x32_bf16( \
            a0[MB + mi][0], fb0[ni][0], acc[MB + mi][ni], 0, 0, 0); \
        acc[MB + mi][ni] = __builtin_amdgcn_mfma_f32_16x16x32_bf16( \
            a0[MB + mi][1], fb0[ni][1], acc[MB + mi][ni], 0, 0, 0); \
    }
#define T_STG_A(buf, kt, u) \
    llds16(Ag + aSrc[u] + (kt) * 64, TLDS_A(buf) + (u) * 8192 + wOff);
#define T_STG_B(buf, kt, u) \
    llds16(Wg + bSrc[u] + (kt) * 64, TLDS_B(buf) + (u) * 8192 + wOff);

__global__ __launch_bounds__(512, 2)
void gemm_tail(const __hip_bfloat16* __restrict__ Ag,
               const __hip_bfloat16* __restrict__ Wg,
               const float* __restrict__ bias,
               float* __restrict__ C)
{
    extern __shared__ char smem[];

    const int tid = threadIdx.x;
    const int wgid = (blockIdx.x & 7) * (TAIL_WG / 8) + (blockIdx.x >> 3);
    const int qm = wgid / TAIL_QN;
    const int qn = wgid - qm * TAIL_QN;
    const int tile_m = TAIL_M0 + qm * 128;
    const int tile_n = qn * 128;

    const int rd  = tid >> 3;
    const int chs = (((tid & 7) ^ (rd & 7)) * 8);
    int aSrc[2], bSrc[2];
#pragma unroll
    for (int rb = 0; rb < 2; ++rb) {
        int m  = tile_m + rb * 64 + rd;
        int bq = m / NWIN;
        int wq = m - bq * NWIN;
        aSrc[rb] = (bq * LEN + wq) * DIM + chs;
        bSrc[rb] = (tile_n + rb * 64 + rd) * K_DIM + chs;
    }

    const int wave = tid >> 6, lane = tid & 63;
    const int wm = wave >> 2, wn = wave & 3;             // per-wave 64x32
    const int fr = lane & 15, kg = lane >> 4;
    const int sw    = (fr & 7) << 4;
    const int kOff0 = (kg * 16) ^ sw;
    const int kOff1 = kOff0 ^ 64;
    const int aRowB = (wm * 64 + fr) * 128;
    const int bRowB = (wn * 32 + fr) * 128;
    const int wOff  = wave * 1024;

    bh8 a0[4][2], fb0[2][2];
    f32x4 acc[4][2] = {};

    T_STG_A(0, 0, 0); T_STG_A(0, 0, 1); T_STG_B(0, 0, 0); T_STG_B(0, 0, 1);
    T_STG_A(1, 1, 0); T_STG_A(1, 1, 1);
    asm volatile("s_waitcnt vmcnt(2)" ::: "memory");
    __builtin_amdgcn_s_barrier();
    __builtin_amdgcn_sched_barrier(0);

#pragma unroll 1
    for (int it = 0; it < NITER; ++it) {
        const int b = 2 * it + 1;
        int c = 2 * it + 2; if (c >= NTILE) c = NTILE - 2;
        int d = 2 * it + 3; if (d >= NTILE) d = NTILE - 1;

        T_RD(0);
        T_STG_B(1, b, 0); T_STG_B(1, b, 1);
        PH_MID; T_MFMA(0); PH_END;

        T_STG_A(0, c, 0); T_STG_A(0, c, 1);
        PH_MID; T_MFMA(2); PH_END_VM(2);

        T_RD(1);
        T_STG_B(0, c, 0); T_STG_B(0, c, 1);
        PH_MID; T_MFMA(0); PH_END;

        T_STG_A(1, d, 0); T_STG_A(1, d, 1);
        PH_MID; T_MFMA(2); PH_END_VM(2);
    }

    float bv[2];
    const float* bp = bias + tile_n + wn * 32 + fr;
#pragma unroll
    for (int ni = 0; ni < 2; ++ni) bv[ni] = bp[ni * 16];

    const int r0 = (lane >> 4) * 4;
#pragma unroll
    for (int mi = 0; mi < 4; ++mi) {
#pragma unroll
        for (int j = 0; j < 4; ++j) {
            long m = tile_m + wm * 64 + mi * 16 + r0 + j;
            float* crow = C + m * (long)N_DIM + tile_n + wn * 32 + fr;
#pragma unroll
            for (int ni = 0; ni < 2; ++ni)
                __builtin_nontemporal_store(acc[mi][ni][j] + bv[ni], &crow[ni * 16]);
        }
    }
}

extern "C" void kernel_launch(void* const* d_in, const int* in_sizes, int n_in,
                              void* d_out, int out_size, void* d_ws, size_t ws_size,
                              hipStream_t stream) {
    const float* inp  = (const float*)d_in[0];
    const float* Wf   = (const float*)d_in[1];
    const float* bias = (const float*)d_in[2];
    float* out = (float*)d_out;

    __hip_bfloat16* Abf = (__hip_bfloat16*)d_ws;
    __hip_bfloat16* Wbf = (__hip_bfloat16*)((char*)d_ws + (size_t)BATCH * LEN * DIM * 2);

    const int nA8 = BATCH * LEN * DIM / 8;
    const int nW8 = N_DIM * K_DIM / 8;
    cvt_f32_bf16<<<(nA8 + 255) / 256, 256, 0, stream>>>(inp, Abf, nA8);
    cvt_f32_bf16<<<(nW8 + 255) / 256, 256, 0, stream>>>(Wf, Wbf, nW8);

    hipFuncSetAttribute((const void*)gemm_bulk,
                        hipFuncAttributeMaxDynamicSharedMemorySize, 131072);
    hipFuncSetAttribute((const void*)gemm_tail,
                        hipFuncAttributeMaxDynamicSharedMemorySize, 65536);
    gemm_bulk<<<dim3(BULK_WG), 512, 131072, stream>>>(Abf, Wbf, bias, out);
    gemm_tail<<<dim3(TAIL_WG), 512, 65536, stream>>>(Abf, Wbf, bias, out);
}